// Round 12
// baseline (71.231 us; speedup 1.0000x reference)
//
#include <hip/hip_runtime.h>
#include <math.h>

static constexpr int Bn = 64;
static constexpr int Nn = 64;
static constexpr int Mn = 10;
static constexpr int Dn = 512;
static constexpr int NMn = Nn * Mn;      // 640
static constexpr int RT = 32;            // rows per block (kernel 2)
static constexpr int NBLK2 = Bn * (NMn / RT);  // 1280
static constexpr float EPSV = 1e-12f;

typedef unsigned short u16;
typedef unsigned int u32;
typedef __attribute__((ext_vector_type(8))) __bf16 bf16x8;
typedef __attribute__((ext_vector_type(4))) float f32x4;

static __device__ __forceinline__ u16 f2bf(float f) {
  u32 u = __float_as_uint(f);
  u = u + 0x7fffu + ((u >> 16) & 1u);   // round-to-nearest-even
  return (u16)(u >> 16);
}

// ---------------- fast path (round-11, k2 instrumented via double-launch) ----
// ch2 layout: [b][kblk=k/32][n][koff=k%32] bf16

__global__ __launch_bounds__(256) void centroid_k(const float* __restrict__ x,
                                                  u16* __restrict__ ch2,
                                                  float* __restrict__ out) {
  const int bn = blockIdx.x;          // b*Nn + n
  const int tid = threadIdx.x;
  const int f4 = tid & 127;
  const int mg = tid >> 7;
  const int wv = tid >> 6, ln = tid & 63;
  const float4* xp = (const float4*)(x + (size_t)bn * (Mn * Dn));

  if (bn == 0 && tid == 0) out[0] = 0.f;

  float4 a = {0.f, 0.f, 0.f, 0.f};
#pragma unroll
  for (int k = 0; k < 5; ++k) {
    const float4 v = xp[(2 * k + mg) * 128 + f4];
    a.x += v.x; a.y += v.y; a.z += v.z; a.w += v.w;
  }
  __shared__ float4 cred[128];
  if (mg == 1) cred[f4] = a;
  __syncthreads();

  float4 c = {0.f, 0.f, 0.f, 0.f};
  float cs = 0.f;
  if (mg == 0) {
    c = cred[f4];
    c.x += a.x; c.y += a.y; c.z += a.z; c.w += a.w;
    cs = c.x * c.x + c.y * c.y + c.z * c.z + c.w * c.w;
  }
#pragma unroll
  for (int t = 1; t < 64; t <<= 1) cs += __shfl_xor(cs, t, 64);
  __shared__ float csred[2];
  if (mg == 0 && ln == 0) csred[wv] = cs;
  __syncthreads();
  if (mg == 0) {
    const float scale = 1.0f / fmaxf(sqrtf(csred[0] + csred[1]), EPSV);
    const u16 h0 = f2bf(c.x * scale), h1 = f2bf(c.y * scale);
    const u16 h2 = f2bf(c.z * scale), h3 = f2bf(c.w * scale);
    uint2 w;
    w.x = (u32)h0 | ((u32)h1 << 16);
    w.y = (u32)h2 | ((u32)h3 << 16);
    const int n = bn & (Nn - 1), bb = bn >> 6;
    const size_t off = (((size_t)bb * 16 + (f4 >> 3)) * Nn + n) * 32 + ((f4 & 7) * 4);
    *(uint2*)(ch2 + off) = w;
  }
}

// Kernel 2 (round-8/11 verified body). dst/use_bid: real pass -> (out, 0);
// probe pass -> (scratch, 1) so each block hits a distinct address.
__global__ __launch_bounds__(512) void gemm_loss_k(const float* __restrict__ x,
                                                   const u16* __restrict__ ch2,
                                                   const float* __restrict__ wp,
                                                   const float* __restrict__ bp,
                                                   float* __restrict__ dst,
                                                   int use_bid) {
  __shared__ float S[8][16][65];   // per-wave partial sims, 33.3 KB
  __shared__ float SQ[2][4][16];
  __shared__ float nred[8];

  const int b = blockIdx.x / (NMn / RT);
  const int rt = blockIdx.x % (NMn / RT);
  const int row0 = rt * RT;
  const int tid = threadIdx.x, wv = tid >> 6, ln = tid & 63;
  const int lr = ln & 15;
  const int lkb = (ln >> 4) * 8;
  const int rh = wv >> 2;
  const int q = wv & 3;
  const int k0 = q * 128;

  const float* arow = x + ((size_t)b * NMn + row0 + rh * 16 + lr) * Dn + k0 + lkb;
  const u16* brow = ch2 + (((size_t)b * 16 + q * 4) * Nn) * 32 + (size_t)lr * 32 + lkb;

  f32x4 acc0 = {0.f, 0.f, 0.f, 0.f};
  f32x4 acc1 = acc0, acc2 = acc0, acc3 = acc0;
  float sq = 0.f;

#pragma unroll
  for (int kk = 0; kk < 128; kk += 32) {
    const u16* bp8 = brow + (size_t)(kk >> 5) * (Nn * 32);
    const float4 f0 = *(const float4*)(arow + kk);
    const float4 f1 = *(const float4*)(arow + kk + 4);
    const bf16x8 b0 = *(const bf16x8*)(bp8);
    const bf16x8 b1 = *(const bf16x8*)(bp8 + 16 * 32);
    const bf16x8 b2 = *(const bf16x8*)(bp8 + 32 * 32);
    const bf16x8 b3 = *(const bf16x8*)(bp8 + 48 * 32);
    const float v[8] = {f0.x, f0.y, f0.z, f0.w, f1.x, f1.y, f1.z, f1.w};
    bf16x8 ah;
#pragma unroll
    for (int i = 0; i < 8; ++i) {
      ah[i] = (__bf16)v[i];
      sq = fmaf(v[i], v[i], sq);
    }
    acc0 = __builtin_amdgcn_mfma_f32_16x16x32_bf16(ah, b0, acc0, 0, 0, 0);
    acc1 = __builtin_amdgcn_mfma_f32_16x16x32_bf16(ah, b1, acc1, 0, 0, 0);
    acc2 = __builtin_amdgcn_mfma_f32_16x16x32_bf16(ah, b2, acc2, 0, 0, 0);
    acc3 = __builtin_amdgcn_mfma_f32_16x16x32_bf16(ah, b3, acc3, 0, 0, 0);
  }

  sq += __shfl_xor(sq, 16, 64);
  sq += __shfl_xor(sq, 32, 64);
  if (ln < 16) SQ[rh][q][lr] = sq;

  const int orow = (ln >> 4) * 4;
#pragma unroll
  for (int r = 0; r < 4; ++r) {
    S[wv][orow + r][lr] = acc0[r];
    S[wv][orow + r][16 + lr] = acc1[r];
    S[wv][orow + r][32 + lr] = acc2[r];
    S[wv][orow + r][48 + lr] = acc3[r];
  }
  __syncthreads();

  const float W = *wp, Bb = *bp;
  float acc_nll = 0.f;
#pragma unroll
  for (int i = 0; i < 4; ++i) {
    const int R = wv * 4 + i;
    const int rhh = R >> 4, rl = R & 15;
    const int krow = row0 + R;
    const int spk = krow / Mn;
    const float rn = S[rhh * 4 + 0][rl][ln] + S[rhh * 4 + 1][rl][ln] +
                     S[rhh * 4 + 2][rl][ln] + S[rhh * 4 + 3][rl][ln];
    const float x2 = SQ[rhh][0][rl] + SQ[rhh][1][rl] + SQ[rhh][2][rl] + SQ[rhh][3][rl];
    const float xn = sqrtf(x2);
    const float inv_xn = 1.0f / fmaxf(xn, EPSV);
    const float rspk = __shfl(rn, spk, 64);
    float sv = rn * inv_xn;
    if (ln == spk) {
      const float num = (float)Mn * rspk - x2;
      const float en = sqrtf(fmaxf((float)(Mn * Mn) - 2.0f * (float)Mn * rspk + x2, 0.f));
      sv = num / fmaxf(xn * en, EPSV);
    }
    const float logit = W * sv + Bb;
    const float lspk = __shfl(logit, spk, 64);
    float mx = logit;
#pragma unroll
    for (int t = 1; t < 64; t <<= 1) mx = fmaxf(mx, __shfl_xor(mx, t, 64));
    float se = expf(logit - mx);
#pragma unroll
    for (int t = 1; t < 64; t <<= 1) se += __shfl_xor(se, t, 64);
    acc_nll += (mx + logf(se)) - lspk;
  }
  if (ln == 0) nred[wv] = acc_nll;
  __syncthreads();
  if (tid == 0) {
    float s = 0.f;
#pragma unroll
    for (int i = 0; i < 8; ++i) s += nred[i];
    const int idx = use_bid ? blockIdx.x : 0;
    atomicAdd(dst + idx, s * (1.0f / (float)(Bn * NMn)));
  }
}

// ---------------- fallback path (round-1 structure, known-good) ----------------
static constexpr int ROWS = 8;
static constexpr int DCHUNK = 128;
static constexpr int CPAD = DCHUNK + 1;

__global__ __launch_bounds__(256) void centroid_fb_k(const float* __restrict__ x,
                                                     float* __restrict__ c) {
  const int bn = blockIdx.x;
  const float* xp = x + (size_t)bn * Mn * Dn;
  const int tid = threadIdx.x;
  float a0 = 0.f, a1 = 0.f;
#pragma unroll
  for (int m = 0; m < Mn; ++m) {
    a0 += xp[m * Dn + tid];
    a1 += xp[m * Dn + tid + 256];
  }
  float s = a0 * a0 + a1 * a1;
#pragma unroll
  for (int m = 1; m < 64; m <<= 1) s += __shfl_xor(s, m, 64);
  __shared__ float red[4];
  const int wv = tid >> 6, ln = tid & 63;
  if (ln == 0) red[wv] = s;
  __syncthreads();
  const float tot = red[0] + red[1] + red[2] + red[3];
  const float scale = 1.0f / fmaxf(sqrtf(tot), EPSV);
  float* cp = c + (size_t)bn * Dn;
  cp[tid] = a0 * scale;
  cp[tid + 256] = a1 * scale;
}

__global__ __launch_bounds__(256) void loss_fb_k(const float* __restrict__ x,
                                                 const float* __restrict__ c,
                                                 const float* __restrict__ wp,
                                                 const float* __restrict__ bp,
                                                 float* __restrict__ out) {
  __shared__ __align__(16) float x_lds[ROWS * Dn];
  __shared__ float c_lds[Nn * CPAD];
  __shared__ float xn2s[ROWS];
  __shared__ float sim_lds[ROWS][Nn];

  const int tid = threadIdx.x;
  const int b = blockIdx.x / (NMn / ROWS);
  const int rblk = blockIdx.x % (NMn / ROWS);
  const int row0 = rblk * ROWS;
  const float* xrow = x + ((size_t)b * NMn + row0) * Dn;
  {
    const float4* xs = (const float4*)xrow;
    float4* xd = (float4*)x_lds;
#pragma unroll
    for (int i = tid; i < ROWS * Dn / 4; i += 256) xd[i] = xs[i];
  }
  __syncthreads();
  const int wv = tid >> 6, ln = tid & 63;
  for (int r = wv; r < ROWS; r += 4) {
    float s = 0.f;
#pragma unroll
    for (int j = ln; j < Dn; j += 64) {
      const float v = x_lds[r * Dn + j];
      s += v * v;
    }
#pragma unroll
    for (int m = 1; m < 64; m <<= 1) s += __shfl_xor(s, m, 64);
    if (ln == 0) xn2s[r] = s;
  }
  const int n = tid & 63;
  const int rg = tid >> 6;
  const int r0 = rg * 2, r1 = rg * 2 + 1;
  float s0 = 0.f, s1 = 0.f;
  const float* cb_base = c + (size_t)b * Nn * Dn;
  for (int cb = 0; cb < Dn; cb += DCHUNK) {
    __syncthreads();
    for (int i = tid; i < Nn * DCHUNK; i += 256) {
      const int nn = i / DCHUNK;
      const int j = i & (DCHUNK - 1);
      c_lds[nn * CPAD + j] = cb_base[(size_t)nn * Dn + cb + j];
    }
    __syncthreads();
#pragma unroll 16
    for (int j = 0; j < DCHUNK; ++j) {
      const float cv = c_lds[n * CPAD + j];
      s0 = fmaf(x_lds[r0 * Dn + cb + j], cv, s0);
      s1 = fmaf(x_lds[r1 * Dn + cb + j], cv, s1);
    }
  }
  sim_lds[r0][n] = s0;
  sim_lds[r1][n] = s1;
  __syncthreads();
  const float W = *wp, Bb = *bp;
  float acc_nll = 0.f;
  for (int r = wv; r < ROWS; r += 4) {
    const int k = row0 + r;
    const int spk = k / Mn;
    const float rn = sim_lds[r][ln];
    const float x2 = xn2s[r];
    const float xn = sqrtf(x2);
    const float inv_xn = 1.0f / fmaxf(xn, EPSV);
    const float rspk = sim_lds[r][spk];
    float sv = rn * inv_xn;
    if (ln == spk) {
      const float num = (float)Mn * rspk - x2;
      const float en = sqrtf(fmaxf((float)(Mn * Mn) - 2.0f * (float)Mn * rspk + x2, 0.f));
      sv = num / fmaxf(xn * en, EPSV);
    }
    const float logit = W * sv + Bb;
    const float lspk = __shfl(logit, spk, 64);
    float mx = logit;
#pragma unroll
    for (int m = 1; m < 64; m <<= 1) mx = fmaxf(mx, __shfl_xor(mx, m, 64));
    float se = expf(logit - mx);
#pragma unroll
    for (int m = 1; m < 64; m <<= 1) se += __shfl_xor(se, m, 64);
    acc_nll += (mx + logf(se)) - lspk;
  }
  __shared__ float nred[4];
  if (ln == 0) nred[wv] = acc_nll;
  __syncthreads();
  if (tid == 0)
    atomicAdd(out, (nred[0] + nred[1] + nred[2] + nred[3]) * (1.0f / (float)(Bn * NMn)));
}

extern "C" void kernel_launch(void* const* d_in, const int* in_sizes, int n_in,
                              void* d_out, int out_size, void* d_ws, size_t ws_size,
                              hipStream_t stream) {
  const float* x = (const float*)d_in[0];
  const float* w = (const float*)d_in[1];
  const float* b = (const float*)d_in[2];
  float* out = (float*)d_out;

  const size_t CSZ = (size_t)Bn * 16 * Nn * 32 * sizeof(u16);   // 4,194,304
  const size_t SCR = (size_t)NBLK2 * sizeof(float);             //     5,120
  const size_t NEED = CSZ + SCR;

  if (ws_size >= NEED) {
    u16* ch2 = (u16*)d_ws;
    float* scratch = (float*)((char*)d_ws + CSZ);   // probe sink, never read
    hipLaunchKernelGGL(centroid_k, dim3(Bn * Nn), dim3(256), 0, stream, x, ch2, out);
    // PROBE pass: identical k2, per-block scratch sink (measures k2 duration
    // as the dur delta vs round 11's 46.8 us).
    hipLaunchKernelGGL(gemm_loss_k, dim3(NBLK2), dim3(512), 0, stream,
                       x, ch2, w, b, scratch, 1);
    // REAL pass.
    hipLaunchKernelGGL(gemm_loss_k, dim3(NBLK2), dim3(512), 0, stream,
                       x, ch2, w, b, out, 0);
  } else {
    float* c = (float*)d_ws;  // 8 MB
    hipMemsetAsync(out, 0, sizeof(float), stream);
    hipLaunchKernelGGL(centroid_fb_k, dim3(Bn * Nn), dim3(256), 0, stream, x, c);
    hipLaunchKernelGGL(loss_fb_k, dim3(Bn * (NMn / ROWS)), dim3(256), 0, stream,
                       x, c, w, b, out);
  }
}

// Round 13
// 46.057 us; speedup vs baseline: 1.5466x; 1.5466x over previous
//
#include <hip/hip_runtime.h>
#include <math.h>

static constexpr int Bn = 64;
static constexpr int Nn = 64;
static constexpr int Mn = 10;
static constexpr int Dn = 512;
static constexpr int NMn = Nn * Mn;      // 640
static constexpr int RT = 32;            // rows per block (kernel 2)
static constexpr int NBLK2 = Bn * (NMn / RT);  // 1280
static constexpr float EPSV = 1e-12f;

typedef unsigned short u16;
typedef unsigned int u32;
typedef __attribute__((ext_vector_type(8))) __bf16 bf16x8;
typedef __attribute__((ext_vector_type(4))) float f32x4;

static __device__ __forceinline__ u16 f2bf(float f) {
  u32 u = __float_as_uint(f);
  u = u + 0x7fffu + ((u >> 16) & 1u);   // round-to-nearest-even
  return (u16)(u >> 16);
}

// ---------------- fast path ----------------
// ch2 layout: [b][kblk=k/32][n][koff=k%32] bf16

// Kernel 1: per (b,n): normalized centroid -> bf16 tiled; block 0 zeroes out.
__global__ __launch_bounds__(256) void centroid_k(const float* __restrict__ x,
                                                  u16* __restrict__ ch2,
                                                  float* __restrict__ out) {
  const int bn = blockIdx.x;          // b*Nn + n
  const int tid = threadIdx.x;
  const int f4 = tid & 127;
  const int mg = tid >> 7;
  const int wv = tid >> 6, ln = tid & 63;
  const float4* xp = (const float4*)(x + (size_t)bn * (Mn * Dn));

  if (bn == 0 && tid == 0) out[0] = 0.f;

  float4 a = {0.f, 0.f, 0.f, 0.f};
#pragma unroll
  for (int k = 0; k < 5; ++k) {
    const float4 v = xp[(2 * k + mg) * 128 + f4];
    a.x += v.x; a.y += v.y; a.z += v.z; a.w += v.w;
  }
  __shared__ float4 cred[128];
  if (mg == 1) cred[f4] = a;
  __syncthreads();

  float4 c = {0.f, 0.f, 0.f, 0.f};
  float cs = 0.f;
  if (mg == 0) {
    c = cred[f4];
    c.x += a.x; c.y += a.y; c.z += a.z; c.w += a.w;
    cs = c.x * c.x + c.y * c.y + c.z * c.z + c.w * c.w;
  }
#pragma unroll
  for (int t = 1; t < 64; t <<= 1) cs += __shfl_xor(cs, t, 64);
  __shared__ float csred[2];
  if (mg == 0 && ln == 0) csred[wv] = cs;
  __syncthreads();
  if (mg == 0) {
    const float scale = 1.0f / fmaxf(sqrtf(csred[0] + csred[1]), EPSV);
    const u16 h0 = f2bf(c.x * scale), h1 = f2bf(c.y * scale);
    const u16 h2 = f2bf(c.z * scale), h3 = f2bf(c.w * scale);
    uint2 w;
    w.x = (u32)h0 | ((u32)h1 << 16);
    w.y = (u32)h2 | ((u32)h3 << 16);
    const int n = bn & (Nn - 1), bb = bn >> 6;
    const size_t off = (((size_t)bb * 16 + (f4 >> 3)) * Nn + n) * 32 + ((f4 & 7) * 4);
    *(uint2*)(ch2 + off) = w;
  }
}

// Kernel 2: round-8 verified K-loop (bit-identical sims); DS-slim epilogue:
// no max-subtraction (logits in [-15,5], fp32-safe), no bpermutes (lane spk
// owns its own rn/logit), one deferred cross-lane nll reduce per wave.
__global__ __launch_bounds__(512) void gemm_loss_k(const float* __restrict__ x,
                                                   const u16* __restrict__ ch2,
                                                   const float* __restrict__ wp,
                                                   const float* __restrict__ bp,
                                                   float* __restrict__ out) {
  __shared__ float S[8][16][65];   // per-wave partial sims, 33.3 KB
  __shared__ float SQ[2][4][16];   // per (row-half, K-quarter) row sq-norms
  __shared__ float nred[8];

  const int b = blockIdx.x / (NMn / RT);
  const int rt = blockIdx.x % (NMn / RT);
  const int row0 = rt * RT;
  const int tid = threadIdx.x, wv = tid >> 6, ln = tid & 63;
  const int lr = ln & 15;          // A-row / B-col fragment index
  const int lkb = (ln >> 4) * 8;   // k offset within 32-wide K-step
  const int rh = wv >> 2;          // row-half (0/1)
  const int q = wv & 3;            // K-quarter
  const int k0 = q * 128;

  const float* arow = x + ((size_t)b * NMn + row0 + rh * 16 + lr) * Dn + k0 + lkb;
  const u16* brow = ch2 + (((size_t)b * 16 + q * 4) * Nn) * 32 + (size_t)lr * 32 + lkb;

  f32x4 acc0 = {0.f, 0.f, 0.f, 0.f};
  f32x4 acc1 = acc0, acc2 = acc0, acc3 = acc0;
  float sq = 0.f;

#pragma unroll
  for (int kk = 0; kk < 128; kk += 32) {
    const u16* bp8 = brow + (size_t)(kk >> 5) * (Nn * 32);
    const float4 f0 = *(const float4*)(arow + kk);
    const float4 f1 = *(const float4*)(arow + kk + 4);
    const bf16x8 b0 = *(const bf16x8*)(bp8);
    const bf16x8 b1 = *(const bf16x8*)(bp8 + 16 * 32);
    const bf16x8 b2 = *(const bf16x8*)(bp8 + 32 * 32);
    const bf16x8 b3 = *(const bf16x8*)(bp8 + 48 * 32);
    const float v[8] = {f0.x, f0.y, f0.z, f0.w, f1.x, f1.y, f1.z, f1.w};
    bf16x8 ah;
#pragma unroll
    for (int i = 0; i < 8; ++i) {
      ah[i] = (__bf16)v[i];           // native cast (RNE)
      sq = fmaf(v[i], v[i], sq);
    }
    acc0 = __builtin_amdgcn_mfma_f32_16x16x32_bf16(ah, b0, acc0, 0, 0, 0);
    acc1 = __builtin_amdgcn_mfma_f32_16x16x32_bf16(ah, b1, acc1, 0, 0, 0);
    acc2 = __builtin_amdgcn_mfma_f32_16x16x32_bf16(ah, b2, acc2, 0, 0, 0);
    acc3 = __builtin_amdgcn_mfma_f32_16x16x32_bf16(ah, b3, acc3, 0, 0, 0);
  }

  sq += __shfl_xor(sq, 16, 64);
  sq += __shfl_xor(sq, 32, 64);
  if (ln < 16) SQ[rh][q][lr] = sq;

  // C/D layout: col = lane&15, row = (lane>>4)*4 + reg  (verified rounds 2-12)
  const int orow = (ln >> 4) * 4;
#pragma unroll
  for (int r = 0; r < 4; ++r) {
    S[wv][orow + r][lr] = acc0[r];
    S[wv][orow + r][16 + lr] = acc1[r];
    S[wv][orow + r][32 + lr] = acc2[r];
    S[wv][orow + r][48 + lr] = acc3[r];
  }
  __syncthreads();

  // DS-slim CE: wave wv handles local rows wv*4..wv*4+3; lanes = 64 speakers
  const float W = *wp, Bb = *bp;
  float lane_nll = 0.f;               // per-LANE accumulator
#pragma unroll
  for (int i = 0; i < 4; ++i) {
    const int R = wv * 4 + i;         // local row 0..31
    const int rhh = R >> 4, rl = R & 15;
    const int krow = row0 + R;
    const int spk = krow / Mn;
    const float rn = S[rhh * 4 + 0][rl][ln] + S[rhh * 4 + 1][rl][ln] +
                     S[rhh * 4 + 2][rl][ln] + S[rhh * 4 + 3][rl][ln];
    const float x2 = SQ[rhh][0][rl] + SQ[rhh][1][rl] + SQ[rhh][2][rl] + SQ[rhh][3][rl];
    const float xn = sqrtf(x2);
    const float inv_xn = 1.0f / fmaxf(xn, EPSV);
    float sv = rn * inv_xn;
    if (ln == spk) {                  // lane spk owns rn == rspk
      const float num = (float)Mn * rn - x2;
      const float en = sqrtf(fmaxf((float)(Mn * Mn) - 2.0f * (float)Mn * rn + x2, 0.f));
      sv = num / fmaxf(xn * en, EPSV);
    }
    const float logit = W * sv + Bb;  // in [-15, 5]: exp-sum fp32-safe w/o max
    float e = expf(logit);
#pragma unroll
    for (int t = 1; t < 64; t <<= 1) e += __shfl_xor(e, t, 64);   // se (uniform)
    if (ln == 0) lane_nll += logf(e);
    if (ln == spk) lane_nll -= logit;
  }
#pragma unroll
  for (int t = 1; t < 64; t <<= 1) lane_nll += __shfl_xor(lane_nll, t, 64);
  if (ln == 0) nred[wv] = lane_nll;
  __syncthreads();
  if (tid == 0) {
    float s = 0.f;
#pragma unroll
    for (int i = 0; i < 8; ++i) s += nred[i];
    atomicAdd(out, s * (1.0f / (float)(Bn * NMn)));
  }
}

// ---------------- fallback path (round-1 structure, known-good) ----------------
static constexpr int ROWS = 8;
static constexpr int DCHUNK = 128;
static constexpr int CPAD = DCHUNK + 1;

__global__ __launch_bounds__(256) void centroid_fb_k(const float* __restrict__ x,
                                                     float* __restrict__ c) {
  const int bn = blockIdx.x;
  const float* xp = x + (size_t)bn * Mn * Dn;
  const int tid = threadIdx.x;
  float a0 = 0.f, a1 = 0.f;
#pragma unroll
  for (int m = 0; m < Mn; ++m) {
    a0 += xp[m * Dn + tid];
    a1 += xp[m * Dn + tid + 256];
  }
  float s = a0 * a0 + a1 * a1;
#pragma unroll
  for (int m = 1; m < 64; m <<= 1) s += __shfl_xor(s, m, 64);
  __shared__ float red[4];
  const int wv = tid >> 6, ln = tid & 63;
  if (ln == 0) red[wv] = s;
  __syncthreads();
  const float tot = red[0] + red[1] + red[2] + red[3];
  const float scale = 1.0f / fmaxf(sqrtf(tot), EPSV);
  float* cp = c + (size_t)bn * Dn;
  cp[tid] = a0 * scale;
  cp[tid + 256] = a1 * scale;
}

__global__ __launch_bounds__(256) void loss_fb_k(const float* __restrict__ x,
                                                 const float* __restrict__ c,
                                                 const float* __restrict__ wp,
                                                 const float* __restrict__ bp,
                                                 float* __restrict__ out) {
  __shared__ __align__(16) float x_lds[ROWS * Dn];
  __shared__ float c_lds[Nn * CPAD];
  __shared__ float xn2s[ROWS];
  __shared__ float sim_lds[ROWS][Nn];

  const int tid = threadIdx.x;
  const int b = blockIdx.x / (NMn / ROWS);
  const int rblk = blockIdx.x % (NMn / ROWS);
  const int row0 = rblk * ROWS;
  const float* xrow = x + ((size_t)b * NMn + row0) * Dn;
  {
    const float4* xs = (const float4*)xrow;
    float4* xd = (float4*)x_lds;
#pragma unroll
    for (int i = tid; i < ROWS * Dn / 4; i += 256) xd[i] = xs[i];
  }
  __syncthreads();
  const int wv = tid >> 6, ln = tid & 63;
  for (int r = wv; r < ROWS; r += 4) {
    float s = 0.f;
#pragma unroll
    for (int j = ln; j < Dn; j += 64) {
      const float v = x_lds[r * Dn + j];
      s += v * v;
    }
#pragma unroll
    for (int m = 1; m < 64; m <<= 1) s += __shfl_xor(s, m, 64);
    if (ln == 0) xn2s[r] = s;
  }
  const int n = tid & 63;
  const int rg = tid >> 6;
  const int r0 = rg * 2, r1 = rg * 2 + 1;
  float s0 = 0.f, s1 = 0.f;
  const float* cb_base = c + (size_t)b * Nn * Dn;
  for (int cb = 0; cb < Dn; cb += DCHUNK) {
    __syncthreads();
    for (int i = tid; i < Nn * DCHUNK; i += 256) {
      const int nn = i / DCHUNK;
      const int j = i & (DCHUNK - 1);
      c_lds[nn * CPAD + j] = cb_base[(size_t)nn * Dn + cb + j];
    }
    __syncthreads();
#pragma unroll 16
    for (int j = 0; j < DCHUNK; ++j) {
      const float cv = c_lds[n * CPAD + j];
      s0 = fmaf(x_lds[r0 * Dn + cb + j], cv, s0);
      s1 = fmaf(x_lds[r1 * Dn + cb + j], cv, s1);
    }
  }
  sim_lds[r0][n] = s0;
  sim_lds[r1][n] = s1;
  __syncthreads();
  const float W = *wp, Bb = *bp;
  float acc_nll = 0.f;
  for (int r = wv; r < ROWS; r += 4) {
    const int k = row0 + r;
    const int spk = k / Mn;
    const float rn = sim_lds[r][ln];
    const float x2 = xn2s[r];
    const float xn = sqrtf(x2);
    const float inv_xn = 1.0f / fmaxf(xn, EPSV);
    const float rspk = sim_lds[r][spk];
    float sv = rn * inv_xn;
    if (ln == spk) {
      const float num = (float)Mn * rspk - x2;
      const float en = sqrtf(fmaxf((float)(Mn * Mn) - 2.0f * (float)Mn * rspk + x2, 0.f));
      sv = num / fmaxf(xn * en, EPSV);
    }
    const float logit = W * sv + Bb;
    const float lspk = __shfl(logit, spk, 64);
    float mx = logit;
#pragma unroll
    for (int m = 1; m < 64; m <<= 1) mx = fmaxf(mx, __shfl_xor(mx, m, 64));
    float se = expf(logit - mx);
#pragma unroll
    for (int m = 1; m < 64; m <<= 1) se += __shfl_xor(se, m, 64);
    acc_nll += (mx + logf(se)) - lspk;
  }
  __shared__ float nred[4];
  if (ln == 0) nred[wv] = acc_nll;
  __syncthreads();
  if (tid == 0)
    atomicAdd(out, (nred[0] + nred[1] + nred[2] + nred[3]) * (1.0f / (float)(Bn * NMn)));
}

extern "C" void kernel_launch(void* const* d_in, const int* in_sizes, int n_in,
                              void* d_out, int out_size, void* d_ws, size_t ws_size,
                              hipStream_t stream) {
  const float* x = (const float*)d_in[0];
  const float* w = (const float*)d_in[1];
  const float* b = (const float*)d_in[2];
  float* out = (float*)d_out;

  const size_t CSZ = (size_t)Bn * 16 * Nn * 32 * sizeof(u16);   // 4,194,304
  const size_t NEED = CSZ;

  if (ws_size >= NEED) {
    u16* ch2 = (u16*)d_ws;
    hipLaunchKernelGGL(centroid_k, dim3(Bn * Nn), dim3(256), 0, stream, x, ch2, out);
    hipLaunchKernelGGL(gemm_loss_k, dim3(NBLK2), dim3(512), 0, stream,
                       x, ch2, w, b, out);
  } else {
    float* c = (float*)d_ws;  // 8 MB
    hipMemsetAsync(out, 0, sizeof(float), stream);
    hipLaunchKernelGGL(centroid_fb_k, dim3(Bn * Nn), dim3(256), 0, stream, x, c);
    hipLaunchKernelGGL(loss_fb_k, dim3(Bn * (NMn / ROWS)), dim3(256), 0, stream,
                       x, c, w, b, out);
  }
}

// Round 14
// 45.804 us; speedup vs baseline: 1.5551x; 1.0055x over previous
//
#include <hip/hip_runtime.h>
#include <math.h>

static constexpr int Bn = 64;
static constexpr int Nn = 64;
static constexpr int Mn = 10;
static constexpr int Dn = 512;
static constexpr int NMn = Nn * Mn;      // 640
static constexpr int RT = 32;            // rows per block (kernel 2)
static constexpr int NBLK2 = Bn * (NMn / RT);  // 1280 = 8 * 160
static constexpr float EPSV = 1e-12f;

typedef unsigned short u16;
typedef unsigned int u32;
typedef __attribute__((ext_vector_type(8))) __bf16 bf16x8;
typedef __attribute__((ext_vector_type(4))) float f32x4;

static __device__ __forceinline__ u16 f2bf(float f) {
  u32 u = __float_as_uint(f);
  u = u + 0x7fffu + ((u >> 16) & 1u);   // round-to-nearest-even
  return (u16)(u >> 16);
}

// ---------------- fast path ----------------
// ch2 layout: [b][kblk=k/32][n][koff=k%32] bf16

// Kernel 1: 2 (b,n) tasks per block (40 KB contiguous): 10 independent loads
// in flight per thread; one barrier phase for both tasks. Per-task math is
// bit-identical to rounds 8-13.
__global__ __launch_bounds__(256) void centroid_k(const float* __restrict__ x,
                                                  u16* __restrict__ ch2,
                                                  float* __restrict__ out) {
  const int base = blockIdx.x * 2;    // tasks base, base+1
  const int tid = threadIdx.x;
  const int f4 = tid & 127;
  const int mg = tid >> 7;
  const int wv = tid >> 6, ln = tid & 63;

  if (blockIdx.x == 0 && tid == 0) out[0] = 0.f;

  const float4* xp0 = (const float4*)(x + (size_t)base * (Mn * Dn));
  const float4* xp1 = (const float4*)(x + (size_t)(base + 1) * (Mn * Dn));

  float4 a0 = {0.f, 0.f, 0.f, 0.f}, a1 = {0.f, 0.f, 0.f, 0.f};
#pragma unroll
  for (int k = 0; k < 5; ++k) {
    const float4 v0 = xp0[(2 * k + mg) * 128 + f4];
    const float4 v1 = xp1[(2 * k + mg) * 128 + f4];
    a0.x += v0.x; a0.y += v0.y; a0.z += v0.z; a0.w += v0.w;
    a1.x += v1.x; a1.y += v1.y; a1.z += v1.z; a1.w += v1.w;
  }
  __shared__ float4 cred[2][128];
  if (mg == 1) { cred[0][f4] = a0; cred[1][f4] = a1; }
  __syncthreads();

  float cs0 = 0.f, cs1 = 0.f;
  float4 c0 = {0.f, 0.f, 0.f, 0.f}, c1 = {0.f, 0.f, 0.f, 0.f};
  if (mg == 0) {
    const float4 v0 = cred[0][f4];
    c0.x = a0.x + v0.x; c0.y = a0.y + v0.y; c0.z = a0.z + v0.z; c0.w = a0.w + v0.w;
    cs0 = c0.x * c0.x + c0.y * c0.y + c0.z * c0.z + c0.w * c0.w;
    const float4 v1 = cred[1][f4];
    c1.x = a1.x + v1.x; c1.y = a1.y + v1.y; c1.z = a1.z + v1.z; c1.w = a1.w + v1.w;
    cs1 = c1.x * c1.x + c1.y * c1.y + c1.z * c1.z + c1.w * c1.w;
  }
#pragma unroll
  for (int t = 1; t < 64; t <<= 1) {
    cs0 += __shfl_xor(cs0, t, 64);
    cs1 += __shfl_xor(cs1, t, 64);
  }
  __shared__ float csred[2][2];
  if (mg == 0 && ln == 0) { csred[0][wv] = cs0; csred[1][wv] = cs1; }
  __syncthreads();
  if (mg == 0) {
    const int kblk = f4 >> 3, koff = (f4 & 7) * 4;
#pragma unroll
    for (int t = 0; t < 2; ++t) {
      const int bn = base + t;
      const int n = bn & (Nn - 1), bb = bn >> 6;
      const float scale = 1.0f / fmaxf(sqrtf(csred[t][0] + csred[t][1]), EPSV);
      const float4 c = t ? c1 : c0;
      const u16 h0 = f2bf(c.x * scale), h1 = f2bf(c.y * scale);
      const u16 h2 = f2bf(c.z * scale), h3 = f2bf(c.w * scale);
      uint2 w;
      w.x = (u32)h0 | ((u32)h1 << 16);
      w.y = (u32)h2 | ((u32)h3 << 16);
      const size_t off = (((size_t)bb * 16 + kblk) * Nn + n) * 32 + koff;
      *(uint2*)(ch2 + off) = w;
    }
  }
}

// Kernel 2: round-8 verified K-loop + round-13 DS-slim epilogue, plus a
// chunked XCD swizzle (wgid = (bid&7)*160 + bid>>3, bijective for 1280) so
// each XCD owns 8 consecutive batches -> ch2 panels are XCD-L2-resident.
__global__ __launch_bounds__(512) void gemm_loss_k(const float* __restrict__ x,
                                                   const u16* __restrict__ ch2,
                                                   const float* __restrict__ wp,
                                                   const float* __restrict__ bp,
                                                   float* __restrict__ out) {
  __shared__ float S[8][16][65];   // per-wave partial sims, 33.3 KB
  __shared__ float SQ[2][4][16];
  __shared__ float nred[8];

  const int bid = blockIdx.x;
  const int wgid = (bid & 7) * (NBLK2 / 8) + (bid >> 3);   // XCD-chunked
  const int b = wgid / (NMn / RT);
  const int rt = wgid % (NMn / RT);
  const int row0 = rt * RT;
  const int tid = threadIdx.x, wv = tid >> 6, ln = tid & 63;
  const int lr = ln & 15;
  const int lkb = (ln >> 4) * 8;
  const int rh = wv >> 2;
  const int q = wv & 3;
  const int k0 = q * 128;

  const float* arow = x + ((size_t)b * NMn + row0 + rh * 16 + lr) * Dn + k0 + lkb;
  const u16* brow = ch2 + (((size_t)b * 16 + q * 4) * Nn) * 32 + (size_t)lr * 32 + lkb;

  f32x4 acc0 = {0.f, 0.f, 0.f, 0.f};
  f32x4 acc1 = acc0, acc2 = acc0, acc3 = acc0;
  float sq = 0.f;

#pragma unroll
  for (int kk = 0; kk < 128; kk += 32) {
    const u16* bp8 = brow + (size_t)(kk >> 5) * (Nn * 32);
    const float4 f0 = *(const float4*)(arow + kk);
    const float4 f1 = *(const float4*)(arow + kk + 4);
    const bf16x8 b0 = *(const bf16x8*)(bp8);
    const bf16x8 b1 = *(const bf16x8*)(bp8 + 16 * 32);
    const bf16x8 b2 = *(const bf16x8*)(bp8 + 32 * 32);
    const bf16x8 b3 = *(const bf16x8*)(bp8 + 48 * 32);
    const float v[8] = {f0.x, f0.y, f0.z, f0.w, f1.x, f1.y, f1.z, f1.w};
    bf16x8 ah;
#pragma unroll
    for (int i = 0; i < 8; ++i) {
      ah[i] = (__bf16)v[i];
      sq = fmaf(v[i], v[i], sq);
    }
    acc0 = __builtin_amdgcn_mfma_f32_16x16x32_bf16(ah, b0, acc0, 0, 0, 0);
    acc1 = __builtin_amdgcn_mfma_f32_16x16x32_bf16(ah, b1, acc1, 0, 0, 0);
    acc2 = __builtin_amdgcn_mfma_f32_16x16x32_bf16(ah, b2, acc2, 0, 0, 0);
    acc3 = __builtin_amdgcn_mfma_f32_16x16x32_bf16(ah, b3, acc3, 0, 0, 0);
  }

  sq += __shfl_xor(sq, 16, 64);
  sq += __shfl_xor(sq, 32, 64);
  if (ln < 16) SQ[rh][q][lr] = sq;

  const int orow = (ln >> 4) * 4;
#pragma unroll
  for (int r = 0; r < 4; ++r) {
    S[wv][orow + r][lr] = acc0[r];
    S[wv][orow + r][16 + lr] = acc1[r];
    S[wv][orow + r][32 + lr] = acc2[r];
    S[wv][orow + r][48 + lr] = acc3[r];
  }
  __syncthreads();

  const float W = *wp, Bb = *bp;
  float lane_nll = 0.f;
#pragma unroll
  for (int i = 0; i < 4; ++i) {
    const int R = wv * 4 + i;
    const int rhh = R >> 4, rl = R & 15;
    const int krow = row0 + R;
    const int spk = krow / Mn;
    const float rn = S[rhh * 4 + 0][rl][ln] + S[rhh * 4 + 1][rl][ln] +
                     S[rhh * 4 + 2][rl][ln] + S[rhh * 4 + 3][rl][ln];
    const float x2 = SQ[rhh][0][rl] + SQ[rhh][1][rl] + SQ[rhh][2][rl] + SQ[rhh][3][rl];
    const float xn = sqrtf(x2);
    const float inv_xn = 1.0f / fmaxf(xn, EPSV);
    float sv = rn * inv_xn;
    if (ln == spk) {
      const float num = (float)Mn * rn - x2;
      const float en = sqrtf(fmaxf((float)(Mn * Mn) - 2.0f * (float)Mn * rn + x2, 0.f));
      sv = num / fmaxf(xn * en, EPSV);
    }
    const float logit = W * sv + Bb;   // in [-15,5]: exp-sum fp32-safe w/o max
    float e = expf(logit);
#pragma unroll
    for (int t = 1; t < 64; t <<= 1) e += __shfl_xor(e, t, 64);
    if (ln == 0) lane_nll += logf(e);
    if (ln == spk) lane_nll -= logit;
  }
#pragma unroll
  for (int t = 1; t < 64; t <<= 1) lane_nll += __shfl_xor(lane_nll, t, 64);
  if (ln == 0) nred[wv] = lane_nll;
  __syncthreads();
  if (tid == 0) {
    float s = 0.f;
#pragma unroll
    for (int i = 0; i < 8; ++i) s += nred[i];
    atomicAdd(out, s * (1.0f / (float)(Bn * NMn)));
  }
}

// ---------------- fallback path (round-1 structure, known-good) ----------------
static constexpr int ROWS = 8;
static constexpr int DCHUNK = 128;
static constexpr int CPAD = DCHUNK + 1;

__global__ __launch_bounds__(256) void centroid_fb_k(const float* __restrict__ x,
                                                     float* __restrict__ c) {
  const int bn = blockIdx.x;
  const float* xp = x + (size_t)bn * Mn * Dn;
  const int tid = threadIdx.x;
  float a0 = 0.f, a1 = 0.f;
#pragma unroll
  for (int m = 0; m < Mn; ++m) {
    a0 += xp[m * Dn + tid];
    a1 += xp[m * Dn + tid + 256];
  }
  float s = a0 * a0 + a1 * a1;
#pragma unroll
  for (int m = 1; m < 64; m <<= 1) s += __shfl_xor(s, m, 64);
  __shared__ float red[4];
  const int wv = tid >> 6, ln = tid & 63;
  if (ln == 0) red[wv] = s;
  __syncthreads();
  const float tot = red[0] + red[1] + red[2] + red[3];
  const float scale = 1.0f / fmaxf(sqrtf(tot), EPSV);
  float* cp = c + (size_t)bn * Dn;
  cp[tid] = a0 * scale;
  cp[tid + 256] = a1 * scale;
}

__global__ __launch_bounds__(256) void loss_fb_k(const float* __restrict__ x,
                                                 const float* __restrict__ c,
                                                 const float* __restrict__ wp,
                                                 const float* __restrict__ bp,
                                                 float* __restrict__ out) {
  __shared__ __align__(16) float x_lds[ROWS * Dn];
  __shared__ float c_lds[Nn * CPAD];
  __shared__ float xn2s[ROWS];
  __shared__ float sim_lds[ROWS][Nn];

  const int tid = threadIdx.x;
  const int b = blockIdx.x / (NMn / ROWS);
  const int rblk = blockIdx.x % (NMn / ROWS);
  const int row0 = rblk * ROWS;
  const float* xrow = x + ((size_t)b * NMn + row0) * Dn;
  {
    const float4* xs = (const float4*)xrow;
    float4* xd = (float4*)x_lds;
#pragma unroll
    for (int i = tid; i < ROWS * Dn / 4; i += 256) xd[i] = xs[i];
  }
  __syncthreads();
  const int wv = tid >> 6, ln = tid & 63;
  for (int r = wv; r < ROWS; r += 4) {
    float s = 0.f;
#pragma unroll
    for (int j = ln; j < Dn; j += 64) {
      const float v = x_lds[r * Dn + j];
      s += v * v;
    }
#pragma unroll
    for (int m = 1; m < 64; m <<= 1) s += __shfl_xor(s, m, 64);
    if (ln == 0) xn2s[r] = s;
  }
  const int n = tid & 63;
  const int rg = tid >> 6;
  const int r0 = rg * 2, r1 = rg * 2 + 1;
  float s0 = 0.f, s1 = 0.f;
  const float* cb_base = c + (size_t)b * Nn * Dn;
  for (int cb = 0; cb < Dn; cb += DCHUNK) {
    __syncthreads();
    for (int i = tid; i < Nn * DCHUNK; i += 256) {
      const int nn = i / DCHUNK;
      const int j = i & (DCHUNK - 1);
      c_lds[nn * CPAD + j] = cb_base[(size_t)nn * Dn + cb + j];
    }
    __syncthreads();
#pragma unroll 16
    for (int j = 0; j < DCHUNK; ++j) {
      const float cv = c_lds[n * CPAD + j];
      s0 = fmaf(x_lds[r0 * Dn + cb + j], cv, s0);
      s1 = fmaf(x_lds[r1 * Dn + cb + j], cv, s1);
    }
  }
  sim_lds[r0][n] = s0;
  sim_lds[r1][n] = s1;
  __syncthreads();
  const float W = *wp, Bb = *bp;
  float acc_nll = 0.f;
  for (int r = wv; r < ROWS; r += 4) {
    const int k = row0 + r;
    const int spk = k / Mn;
    const float rn = sim_lds[r][ln];
    const float x2 = xn2s[r];
    const float xn = sqrtf(x2);
    const float inv_xn = 1.0f / fmaxf(xn, EPSV);
    const float rspk = sim_lds[r][spk];
    float sv = rn * inv_xn;
    if (ln == spk) {
      const float num = (float)Mn * rspk - x2;
      const float en = sqrtf(fmaxf((float)(Mn * Mn) - 2.0f * (float)Mn * rspk + x2, 0.f));
      sv = num / fmaxf(xn * en, EPSV);
    }
    const float logit = W * sv + Bb;
    const float lspk = __shfl(logit, spk, 64);
    float mx = logit;
#pragma unroll
    for (int m = 1; m < 64; m <<= 1) mx = fmaxf(mx, __shfl_xor(mx, m, 64));
    float se = expf(logit - mx);
#pragma unroll
    for (int m = 1; m < 64; m <<= 1) se += __shfl_xor(se, m, 64);
    acc_nll += (mx + logf(se)) - lspk;
  }
  __shared__ float nred[4];
  if (ln == 0) nred[wv] = acc_nll;
  __syncthreads();
  if (tid == 0)
    atomicAdd(out, (nred[0] + nred[1] + nred[2] + nred[3]) * (1.0f / (float)(Bn * NMn)));
}

extern "C" void kernel_launch(void* const* d_in, const int* in_sizes, int n_in,
                              void* d_out, int out_size, void* d_ws, size_t ws_size,
                              hipStream_t stream) {
  const float* x = (const float*)d_in[0];
  const float* w = (const float*)d_in[1];
  const float* b = (const float*)d_in[2];
  float* out = (float*)d_out;

  const size_t CSZ = (size_t)Bn * 16 * Nn * 32 * sizeof(u16);   // 4,194,304
  const size_t NEED = CSZ;

  if (ws_size >= NEED) {
    u16* ch2 = (u16*)d_ws;
    hipLaunchKernelGGL(centroid_k, dim3(Bn * Nn / 2), dim3(256), 0, stream,
                       x, ch2, out);
    hipLaunchKernelGGL(gemm_loss_k, dim3(NBLK2), dim3(512), 0, stream,
                       x, ch2, w, b, out);
  } else {
    float* c = (float*)d_ws;  // 8 MB
    hipMemsetAsync(out, 0, sizeof(float), stream);
    hipLaunchKernelGGL(centroid_fb_k, dim3(Bn * Nn), dim3(256), 0, stream, x, c);
    hipLaunchKernelGGL(loss_fb_k, dim3(Bn * (NMn / ROWS)), dim3(256), 0, stream,
                       x, c, w, b, out);
  }
}

// Round 15
// 45.515 us; speedup vs baseline: 1.5650x; 1.0064x over previous
//
#include <hip/hip_runtime.h>
#include <math.h>

static constexpr int Bn = 64;
static constexpr int Nn = 64;
static constexpr int Mn = 10;
static constexpr int Dn = 512;
static constexpr int NMn = Nn * Mn;      // 640
static constexpr int RT = 32;            // rows per block (kernel 2)
static constexpr int NBLK2 = Bn * (NMn / RT);  // 1280 = 8 * 160
static constexpr float EPSV = 1e-12f;

typedef unsigned short u16;
typedef unsigned int u32;
typedef __attribute__((ext_vector_type(8))) __bf16 bf16x8;
typedef __attribute__((ext_vector_type(4))) float f32x4;

static __device__ __forceinline__ u16 f2bf(float f) {
  u32 u = __float_as_uint(f);
  u = u + 0x7fffu + ((u >> 16) & 1u);   // round-to-nearest-even
  return (u16)(u >> 16);
}

// ---------------- fast path ----------------
// ch2 layout: [b][kblk=k/32][n][koff=k%32] bf16

// Kernel 1: 2 (b,n) tasks per block (round-14, bit-identical math).
__global__ __launch_bounds__(256) void centroid_k(const float* __restrict__ x,
                                                  u16* __restrict__ ch2,
                                                  float* __restrict__ out) {
  const int base = blockIdx.x * 2;    // tasks base, base+1
  const int tid = threadIdx.x;
  const int f4 = tid & 127;
  const int mg = tid >> 7;
  const int wv = tid >> 6, ln = tid & 63;

  if (blockIdx.x == 0 && tid == 0) out[0] = 0.f;

  const float4* xp0 = (const float4*)(x + (size_t)base * (Mn * Dn));
  const float4* xp1 = (const float4*)(x + (size_t)(base + 1) * (Mn * Dn));

  float4 a0 = {0.f, 0.f, 0.f, 0.f}, a1 = {0.f, 0.f, 0.f, 0.f};
#pragma unroll
  for (int k = 0; k < 5; ++k) {
    const float4 v0 = xp0[(2 * k + mg) * 128 + f4];
    const float4 v1 = xp1[(2 * k + mg) * 128 + f4];
    a0.x += v0.x; a0.y += v0.y; a0.z += v0.z; a0.w += v0.w;
    a1.x += v1.x; a1.y += v1.y; a1.z += v1.z; a1.w += v1.w;
  }
  __shared__ float4 cred[2][128];
  if (mg == 1) { cred[0][f4] = a0; cred[1][f4] = a1; }
  __syncthreads();

  float cs0 = 0.f, cs1 = 0.f;
  float4 c0 = {0.f, 0.f, 0.f, 0.f}, c1 = {0.f, 0.f, 0.f, 0.f};
  if (mg == 0) {
    const float4 v0 = cred[0][f4];
    c0.x = a0.x + v0.x; c0.y = a0.y + v0.y; c0.z = a0.z + v0.z; c0.w = a0.w + v0.w;
    cs0 = c0.x * c0.x + c0.y * c0.y + c0.z * c0.z + c0.w * c0.w;
    const float4 v1 = cred[1][f4];
    c1.x = a1.x + v1.x; c1.y = a1.y + v1.y; c1.z = a1.z + v1.z; c1.w = a1.w + v1.w;
    cs1 = c1.x * c1.x + c1.y * c1.y + c1.z * c1.z + c1.w * c1.w;
  }
#pragma unroll
  for (int t = 1; t < 64; t <<= 1) {
    cs0 += __shfl_xor(cs0, t, 64);
    cs1 += __shfl_xor(cs1, t, 64);
  }
  __shared__ float csred[2][2];
  if (mg == 0 && ln == 0) { csred[0][wv] = cs0; csred[1][wv] = cs1; }
  __syncthreads();
  if (mg == 0) {
    const int kblk = f4 >> 3, koff = (f4 & 7) * 4;
#pragma unroll
    for (int t = 0; t < 2; ++t) {
      const int bn = base + t;
      const int n = bn & (Nn - 1), bb = bn >> 6;
      const float scale = 1.0f / fmaxf(sqrtf(csred[t][0] + csred[t][1]), EPSV);
      const float4 c = t ? c1 : c0;
      const u16 h0 = f2bf(c.x * scale), h1 = f2bf(c.y * scale);
      const u16 h2 = f2bf(c.z * scale), h3 = f2bf(c.w * scale);
      uint2 w;
      w.x = (u32)h0 | ((u32)h1 << 16);
      w.y = (u32)h2 | ((u32)h3 << 16);
      const size_t off = (((size_t)bb * 16 + kblk) * Nn + n) * 32 + koff;
      *(uint2*)(ch2 + off) = w;
    }
  }
}

// Kernel 2: round-14 verbatim EXCEPT __launch_bounds__(512, 1): lifts the
// 64-VGPR ceiling so the compiler can hoist all 24 independent K-loop loads
// (96 VGPRs of load data) and overlap their latency.
__global__ __launch_bounds__(512, 1) void gemm_loss_k(const float* __restrict__ x,
                                                      const u16* __restrict__ ch2,
                                                      const float* __restrict__ wp,
                                                      const float* __restrict__ bp,
                                                      float* __restrict__ out) {
  __shared__ float S[8][16][65];   // per-wave partial sims, 33.3 KB
  __shared__ float SQ[2][4][16];
  __shared__ float nred[8];

  const int bid = blockIdx.x;
  const int wgid = (bid & 7) * (NBLK2 / 8) + (bid >> 3);   // XCD-chunked
  const int b = wgid / (NMn / RT);
  const int rt = wgid % (NMn / RT);
  const int row0 = rt * RT;
  const int tid = threadIdx.x, wv = tid >> 6, ln = tid & 63;
  const int lr = ln & 15;
  const int lkb = (ln >> 4) * 8;
  const int rh = wv >> 2;
  const int q = wv & 3;
  const int k0 = q * 128;

  const float* arow = x + ((size_t)b * NMn + row0 + rh * 16 + lr) * Dn + k0 + lkb;
  const u16* brow = ch2 + (((size_t)b * 16 + q * 4) * Nn) * 32 + (size_t)lr * 32 + lkb;

  f32x4 acc0 = {0.f, 0.f, 0.f, 0.f};
  f32x4 acc1 = acc0, acc2 = acc0, acc3 = acc0;
  float sq = 0.f;

#pragma unroll
  for (int kk = 0; kk < 128; kk += 32) {
    const u16* bp8 = brow + (size_t)(kk >> 5) * (Nn * 32);
    const float4 f0 = *(const float4*)(arow + kk);
    const float4 f1 = *(const float4*)(arow + kk + 4);
    const bf16x8 b0 = *(const bf16x8*)(bp8);
    const bf16x8 b1 = *(const bf16x8*)(bp8 + 16 * 32);
    const bf16x8 b2 = *(const bf16x8*)(bp8 + 32 * 32);
    const bf16x8 b3 = *(const bf16x8*)(bp8 + 48 * 32);
    const float v[8] = {f0.x, f0.y, f0.z, f0.w, f1.x, f1.y, f1.z, f1.w};
    bf16x8 ah;
#pragma unroll
    for (int i = 0; i < 8; ++i) {
      ah[i] = (__bf16)v[i];
      sq = fmaf(v[i], v[i], sq);
    }
    acc0 = __builtin_amdgcn_mfma_f32_16x16x32_bf16(ah, b0, acc0, 0, 0, 0);
    acc1 = __builtin_amdgcn_mfma_f32_16x16x32_bf16(ah, b1, acc1, 0, 0, 0);
    acc2 = __builtin_amdgcn_mfma_f32_16x16x32_bf16(ah, b2, acc2, 0, 0, 0);
    acc3 = __builtin_amdgcn_mfma_f32_16x16x32_bf16(ah, b3, acc3, 0, 0, 0);
  }

  sq += __shfl_xor(sq, 16, 64);
  sq += __shfl_xor(sq, 32, 64);
  if (ln < 16) SQ[rh][q][lr] = sq;

  const int orow = (ln >> 4) * 4;
#pragma unroll
  for (int r = 0; r < 4; ++r) {
    S[wv][orow + r][lr] = acc0[r];
    S[wv][orow + r][16 + lr] = acc1[r];
    S[wv][orow + r][32 + lr] = acc2[r];
    S[wv][orow + r][48 + lr] = acc3[r];
  }
  __syncthreads();

  const float W = *wp, Bb = *bp;
  float lane_nll = 0.f;
#pragma unroll
  for (int i = 0; i < 4; ++i) {
    const int R = wv * 4 + i;
    const int rhh = R >> 4, rl = R & 15;
    const int krow = row0 + R;
    const int spk = krow / Mn;
    const float rn = S[rhh * 4 + 0][rl][ln] + S[rhh * 4 + 1][rl][ln] +
                     S[rhh * 4 + 2][rl][ln] + S[rhh * 4 + 3][rl][ln];
    const float x2 = SQ[rhh][0][rl] + SQ[rhh][1][rl] + SQ[rhh][2][rl] + SQ[rhh][3][rl];
    const float xn = sqrtf(x2);
    const float inv_xn = 1.0f / fmaxf(xn, EPSV);
    float sv = rn * inv_xn;
    if (ln == spk) {
      const float num = (float)Mn * rn - x2;
      const float en = sqrtf(fmaxf((float)(Mn * Mn) - 2.0f * (float)Mn * rn + x2, 0.f));
      sv = num / fmaxf(xn * en, EPSV);
    }
    const float logit = W * sv + Bb;   // in [-15,5]: exp-sum fp32-safe w/o max
    float e = expf(logit);
#pragma unroll
    for (int t = 1; t < 64; t <<= 1) e += __shfl_xor(e, t, 64);
    if (ln == 0) lane_nll += logf(e);
    if (ln == spk) lane_nll -= logit;
  }
#pragma unroll
  for (int t = 1; t < 64; t <<= 1) lane_nll += __shfl_xor(lane_nll, t, 64);
  if (ln == 0) nred[wv] = lane_nll;
  __syncthreads();
  if (tid == 0) {
    float s = 0.f;
#pragma unroll
    for (int i = 0; i < 8; ++i) s += nred[i];
    atomicAdd(out, s * (1.0f / (float)(Bn * NMn)));
  }
}

// ---------------- fallback path (round-1 structure, known-good) ----------------
static constexpr int ROWS = 8;
static constexpr int DCHUNK = 128;
static constexpr int CPAD = DCHUNK + 1;

__global__ __launch_bounds__(256) void centroid_fb_k(const float* __restrict__ x,
                                                     float* __restrict__ c) {
  const int bn = blockIdx.x;
  const float* xp = x + (size_t)bn * Mn * Dn;
  const int tid = threadIdx.x;
  float a0 = 0.f, a1 = 0.f;
#pragma unroll
  for (int m = 0; m < Mn; ++m) {
    a0 += xp[m * Dn + tid];
    a1 += xp[m * Dn + tid + 256];
  }
  float s = a0 * a0 + a1 * a1;
#pragma unroll
  for (int m = 1; m < 64; m <<= 1) s += __shfl_xor(s, m, 64);
  __shared__ float red[4];
  const int wv = tid >> 6, ln = tid & 63;
  if (ln == 0) red[wv] = s;
  __syncthreads();
  const float tot = red[0] + red[1] + red[2] + red[3];
  const float scale = 1.0f / fmaxf(sqrtf(tot), EPSV);
  float* cp = c + (size_t)bn * Dn;
  cp[tid] = a0 * scale;
  cp[tid + 256] = a1 * scale;
}

__global__ __launch_bounds__(256) void loss_fb_k(const float* __restrict__ x,
                                                 const float* __restrict__ c,
                                                 const float* __restrict__ wp,
                                                 const float* __restrict__ bp,
                                                 float* __restrict__ out) {
  __shared__ __align__(16) float x_lds[ROWS * Dn];
  __shared__ float c_lds[Nn * CPAD];
  __shared__ float xn2s[ROWS];
  __shared__ float sim_lds[ROWS][Nn];

  const int tid = threadIdx.x;
  const int b = blockIdx.x / (NMn / ROWS);
  const int rblk = blockIdx.x % (NMn / ROWS);
  const int row0 = rblk * ROWS;
  const float* xrow = x + ((size_t)b * NMn + row0) * Dn;
  {
    const float4* xs = (const float4*)xrow;
    float4* xd = (float4*)x_lds;
#pragma unroll
    for (int i = tid; i < ROWS * Dn / 4; i += 256) xd[i] = xs[i];
  }
  __syncthreads();
  const int wv = tid >> 6, ln = tid & 63;
  for (int r = wv; r < ROWS; r += 4) {
    float s = 0.f;
#pragma unroll
    for (int j = ln; j < Dn; j += 64) {
      const float v = x_lds[r * Dn + j];
      s += v * v;
    }
#pragma unroll
    for (int m = 1; m < 64; m <<= 1) s += __shfl_xor(s, m, 64);
    if (ln == 0) xn2s[r] = s;
  }
  const int n = tid & 63;
  const int rg = tid >> 6;
  const int r0 = rg * 2, r1 = rg * 2 + 1;
  float s0 = 0.f, s1 = 0.f;
  const float* cb_base = c + (size_t)b * Nn * Dn;
  for (int cb = 0; cb < Dn; cb += DCHUNK) {
    __syncthreads();
    for (int i = tid; i < Nn * DCHUNK; i += 256) {
      const int nn = i / DCHUNK;
      const int j = i & (DCHUNK - 1);
      c_lds[nn * CPAD + j] = cb_base[(size_t)nn * Dn + cb + j];
    }
    __syncthreads();
#pragma unroll 16
    for (int j = 0; j < DCHUNK; ++j) {
      const float cv = c_lds[n * CPAD + j];
      s0 = fmaf(x_lds[r0 * Dn + cb + j], cv, s0);
      s1 = fmaf(x_lds[r1 * Dn + cb + j], cv, s1);
    }
  }
  sim_lds[r0][n] = s0;
  sim_lds[r1][n] = s1;
  __syncthreads();
  const float W = *wp, Bb = *bp;
  float acc_nll = 0.f;
  for (int r = wv; r < ROWS; r += 4) {
    const int k = row0 + r;
    const int spk = k / Mn;
    const float rn = sim_lds[r][ln];
    const float x2 = xn2s[r];
    const float xn = sqrtf(x2);
    const float inv_xn = 1.0f / fmaxf(xn, EPSV);
    const float rspk = sim_lds[r][spk];
    float sv = rn * inv_xn;
    if (ln == spk) {
      const float num = (float)Mn * rspk - x2;
      const float en = sqrtf(fmaxf((float)(Mn * Mn) - 2.0f * (float)Mn * rspk + x2, 0.f));
      sv = num / fmaxf(xn * en, EPSV);
    }
    const float logit = W * sv + Bb;
    const float lspk = __shfl(logit, spk, 64);
    float mx = logit;
#pragma unroll
    for (int m = 1; m < 64; m <<= 1) mx = fmaxf(mx, __shfl_xor(mx, m, 64));
    float se = expf(logit - mx);
#pragma unroll
    for (int m = 1; m < 64; m <<= 1) se += __shfl_xor(se, m, 64);
    acc_nll += (mx + logf(se)) - lspk;
  }
  __shared__ float nred[4];
  if (ln == 0) nred[wv] = acc_nll;
  __syncthreads();
  if (tid == 0)
    atomicAdd(out, (nred[0] + nred[1] + nred[2] + nred[3]) * (1.0f / (float)(Bn * NMn)));
}

extern "C" void kernel_launch(void* const* d_in, const int* in_sizes, int n_in,
                              void* d_out, int out_size, void* d_ws, size_t ws_size,
                              hipStream_t stream) {
  const float* x = (const float*)d_in[0];
  const float* w = (const float*)d_in[1];
  const float* b = (const float*)d_in[2];
  float* out = (float*)d_out;

  const size_t CSZ = (size_t)Bn * 16 * Nn * 32 * sizeof(u16);   // 4,194,304
  const size_t NEED = CSZ;

  if (ws_size >= NEED) {
    u16* ch2 = (u16*)d_ws;
    hipLaunchKernelGGL(centroid_k, dim3(Bn * Nn / 2), dim3(256), 0, stream,
                       x, ch2, out);
    hipLaunchKernelGGL(gemm_loss_k, dim3(NBLK2), dim3(512), 0, stream,
                       x, ch2, w, b, out);
  } else {
    float* c = (float*)d_ws;  // 8 MB
    hipMemsetAsync(out, 0, sizeof(float), stream);
    hipLaunchKernelGGL(centroid_fb_k, dim3(Bn * Nn), dim3(256), 0, stream, x, c);
    hipLaunchKernelGGL(loss_fb_k, dim3(Bn * (NMn / ROWS)), dim3(256), 0, stream,
                       x, c, w, b, out);
  }
}